// Round 4
// baseline (72.367 us; speedup 1.0000x reference)
//
#include <hip/hip_runtime.h>
#include <hip/hip_bf16.h>

#define WPB 4                 // waves per block
#define BLOCK (WPB * 64)
#define GRID 768              // 3 blocks/CU x 256 CU

typedef __attribute__((ext_vector_type(8))) short s16x8;   // 8 bf16 (4 VGPRs)
typedef __attribute__((ext_vector_type(4))) float f32x4;   // 16B / MFMA acc

// async global->LDS, 16B per lane, LDS dest = uniform base + lane*16
#define GLL16(gp, lp) __builtin_amdgcn_global_load_lds( \
    (const __attribute__((address_space(1))) void*)(gp), \
    (__attribute__((address_space(3))) void*)(lp), 16, 0, 0)

__device__ __forceinline__ float wave_sum64(float v) {
#pragma unroll
    for (int m = 32; m >= 1; m >>= 1) v += __shfl_xor(v, m, 64);
    return v;
}

__device__ __forceinline__ short bf16b(float x) {          // f32 -> bf16 (RNE)
    union { float f; unsigned u; } c; c.f = x;
    unsigned r = c.u + 0x7FFFu + ((c.u >> 16) & 1u);
    return (short)(r >> 16);
}

__global__ __launch_bounds__(BLOCK, 3) void vecout_mfma(
    const float* __restrict__ atom_out,   // [N,480]; 1e block = cols 128..319
    const float* __restrict__ ln_w,       // [224]; 1e weights at 128..191
    const float* __restrict__ W1_1,       // [64,64] row-major [u][v]
    const float* __restrict__ W2,         // [64]
    const int*   __restrict__ batch_idx,  // [N], sorted
    float* __restrict__ out,              // [B,3]
    int N)
{
    // per-wave 12KB staging buffer: group's 16 atoms x 768B (f32, swizzled)
    __shared__ __align__(16) char Ash[WPB][12288];
    __shared__ float invsh[WPB][16];

    const int lane  = threadIdx.x & 63;
    const int wid   = threadIdx.x >> 6;
    const int col   = lane & 15;          // B col / C col (v within tile)
    const int kgrp  = lane >> 4;          // k-group
    const int atomi = lane & 15;          // A row (atom-local)

    // ---- balanced contiguous group partition across all waves ----
    const int NG  = (N + 15) >> 4;
    const int NW  = gridDim.x * WPB;
    const int w   = blockIdx.x * WPB + wid;
    const int cpw = NG / NW, rem = NG % NW;
    const int g0  = w * cpw + min(w, rem);
    const int cnt = cpw + (w < rem ? 1 : 0);
    if (cnt <= 0) return;                 // no block barriers -> safe
    const int gend = g0 + cnt;

    // ---- B fragments: W'[k][v] = W1_1[k][v] * ln_w[128+k] * (1/sqrt(64)) ----
    s16x8 Bf[2][4];
#pragma unroll
    for (int kt = 0; kt < 2; ++kt)
#pragma unroll
        for (int nt = 0; nt < 4; ++nt) {
            s16x8 b;
#pragma unroll
            for (int j = 0; j < 8; ++j) {
                int k = kt * 32 + kgrp * 8 + j;
                float wgt = W1_1[k * 64 + nt * 16 + col] * ln_w[128 + k] * 0.125f;
                b[j] = bf16b(wgt);
            }
            Bf[kt][nt] = b;
        }
    float w2r[4];
#pragma unroll
    for (int nt = 0; nt < 4; ++nt) w2r[nt] = W2[nt * 16 + col] * 0.125f;

    // ---- per-instr global source offsets within a group's 30720B span ----
    // physical LDS P = c*1024 + lane*16 ; row = P/768 (768 = 6 cache lines,
    // so the XOR of bits 4..6 never crosses a row); logical L = P ^ key(row).
    int prec[12];
#pragma unroll
    for (int c = 0; c < 12; ++c) {
        int P   = c * 1024 + lane * 16;
        int row = P / 768;
        int L   = P ^ ((row & 7) << 4);
        prec[c] = row * 1920 + 512 + (L - row * 768);   // global bytes from group base
    }

    const char* gb = (const char*)atom_out;
    char* Ab = &Ash[wid][0];

    const unsigned key   = (unsigned)(atomi & 7) << 4;
    const unsigned base0 = (unsigned)(atomi * 768 + kgrp * 96);

    float acc[4][3];
#pragma unroll
    for (int r = 0; r < 4; ++r) { acc[r][0] = 0.f; acc[r][1] = 0.f; acc[r][2] = 0.f; }
    int accb = batch_idx[g0 * 16];

    auto flushAcc = [&]() {
        float s0 = acc[0][0] + acc[1][0] + acc[2][0] + acc[3][0];
        float s1 = acc[0][1] + acc[1][1] + acc[2][1] + acc[3][1];
        float s2 = acc[0][2] + acc[1][2] + acc[2][2] + acc[3][2];
        s0 = wave_sum64(s0); s1 = wave_sum64(s1); s2 = wave_sum64(s2);
        if (lane == 0) {
            // e3nn (y,z,x) -> (x,y,z): out0=c2, out1=c0, out2=c1
            atomicAdd(&out[accb * 3 + 0], s2);
            atomicAdd(&out[accb * 3 + 1], s0);
            atomicAdd(&out[accb * 3 + 2], s1);
        }
#pragma unroll
        for (int r = 0; r < 4; ++r) { acc[r][0] = 0.f; acc[r][1] = 0.f; acc[r][2] = 0.f; }
    };

    auto issueG = [&](int g) {
        if (((g + 1) << 4) <= N) {        // full group (always true when 16|N)
            const char* p = gb + (size_t)g * 30720;
#pragma unroll
            for (int c = 0; c < 12; ++c)
                GLL16(p + prec[c], Ab + c * 1024);
        } else {                           // tail: clamp rows to N-1
#pragma unroll
            for (int c = 0; c < 12; ++c) {
                int P   = c * 1024 + lane * 16;
                int row = P / 768;
                int off = (P ^ ((row & 7) << 4)) - row * 768;
                int ga  = min(g * 16 + row, N - 1);
                GLL16(gb + (size_t)ga * 1920 + 512 + off, Ab + c * 1024);
            }
        }
    };

    issueG(g0);                            // prologue prefetch

    for (int g = g0; g < gend; ++g) {
        int a = g * 16;

        asm volatile("s_waitcnt vmcnt(0)" ::: "memory");   // staged data landed

        // ---- LDS -> regs: lane's 48 floats = two contiguous 96B runs ----
        float F[48];
#pragma unroll
        for (int kt = 0; kt < 2; ++kt)
#pragma unroll
            for (int s = 0; s < 6; ++s) {
                unsigned ad = (base0 + (unsigned)(kt * 384 + s * 16)) ^ key;
                f32x4 t = *(const f32x4*)(Ab + ad);
                int i = (kt * 6 + s) * 4;
                F[i + 0] = t[0]; F[i + 1] = t[1]; F[i + 2] = t[2]; F[i + 3] = t[3];
            }
        asm volatile("s_waitcnt lgkmcnt(0)" ::: "memory"); // reads retired -> buffer dead

        if (g + 1 < gend) issueG(g + 1);   // prefetch next group under compute

        // ---- per-atom RMS norm (4 lanes/atom share via 2 shfls) ----
        float nrm = 0.f;
#pragma unroll
        for (int i = 0; i < 48; ++i) nrm += F[i] * F[i];
        nrm += __shfl_xor(nrm, 16, 64);
        nrm += __shfl_xor(nrm, 32, 64);
        float inv = rsqrtf(nrm * (1.0f / 64.0f) + 1e-5f);
        if (lane < 16) invsh[wid][lane] = inv;

        // ---- build A fragments in-register (no bf16 LDS re-stage) ----
        s16x8 Af[3][2];
#pragma unroll
        for (int c = 0; c < 3; ++c)
#pragma unroll
            for (int kt = 0; kt < 2; ++kt) {
                s16x8 fr;
#pragma unroll
                for (int j = 0; j < 8; ++j) fr[j] = bf16b(F[kt * 24 + 3 * j + c]);
                Af[c][kt] = fr;
            }

        // ---- MFMA: D[atom][v] = sum_u f[atom][u][c] * W'[u][v] ----
        f32x4 Cf[3][4];
#pragma unroll
        for (int c = 0; c < 3; ++c)
#pragma unroll
            for (int nt = 0; nt < 4; ++nt) {
                f32x4 z = {0.f, 0.f, 0.f, 0.f};
                z = __builtin_amdgcn_mfma_f32_16x16x32_bf16(Af[c][0], Bf[0][nt], z, 0, 0, 0);
                z = __builtin_amdgcn_mfma_f32_16x16x32_bf16(Af[c][1], Bf[1][nt], z, 0, 0, 0);
                Cf[c][nt] = z;
            }

        // ---- epilogue: gate + W2; 3 comps of (atom,v) in same lane/reg ----
        float invA[4];
#pragma unroll
        for (int r = 0; r < 4; ++r) invA[r] = invsh[wid][kgrp * 4 + r];

        float part[4][3];
#pragma unroll
        for (int r = 0; r < 4; ++r) {
            part[r][0] = 0.f; part[r][1] = 0.f; part[r][2] = 0.f;
            float iv = invA[r];
#pragma unroll
            for (int nt = 0; nt < 4; ++nt) {
                float g0v = Cf[0][nt][r] * iv;
                float g1v = Cf[1][nt][r] * iv;
                float g2v = Cf[2][nt][r] * iv;
                float q  = g0v * g0v + g1v * g1v + g2v * g2v;
                float nr = sqrtf(q + 1e-12f);
                float sg = 1.f / (1.f + __expf(-nr));
                float t  = sg * w2r[nt];
                part[r][0] += g0v * t; part[r][1] += g1v * t; part[r][2] += g2v * t;
            }
            if (a + kgrp * 4 + r >= N) { part[r][0] = 0.f; part[r][1] = 0.f; part[r][2] = 0.f; }
        }

        // ---- segment accumulation (batch_idx sorted) ----
        int bfst = batch_idx[a];
        int blst = batch_idx[min(a + 15, N - 1)];
        if (bfst == blst) {
            if (bfst != accb) { flushAcc(); accb = bfst; }
#pragma unroll
            for (int r = 0; r < 4; ++r) {
                acc[r][0] += part[r][0]; acc[r][1] += part[r][1]; acc[r][2] += part[r][2];
            }
        } else {
            flushAcc();
#pragma unroll
            for (int r = 0; r < 4; ++r) {
                float c0 = part[r][0], c1 = part[r][1], c2 = part[r][2];
#pragma unroll
                for (int m = 1; m < 16; m <<= 1) {
                    c0 += __shfl_xor(c0, m, 64);
                    c1 += __shfl_xor(c1, m, 64);
                    c2 += __shfl_xor(c2, m, 64);
                }
                int ai = a + kgrp * 4 + r;
                if (col == 0 && ai < N) {
                    int b = batch_idx[ai];
                    atomicAdd(&out[b * 3 + 0], c2);
                    atomicAdd(&out[b * 3 + 1], c0);
                    atomicAdd(&out[b * 3 + 2], c1);
                }
            }
            accb = blst;
        }
    }

    flushAcc();
}

extern "C" void kernel_launch(void* const* d_in, const int* in_sizes, int n_in,
                              void* d_out, int out_size, void* d_ws, size_t ws_size,
                              hipStream_t stream) {
    const float* atom_out  = (const float*)d_in[0];
    const float* ln_w      = (const float*)d_in[2];
    const float* W1_1      = (const float*)d_in[5];
    const float* W2        = (const float*)d_in[7];
    const int*   batch_idx = (const int*)d_in[9];
    float* out = (float*)d_out;

    const int N = in_sizes[0] / 480;

    hipMemsetAsync(d_out, 0, (size_t)out_size * sizeof(float), stream);

    vecout_mfma<<<GRID, BLOCK, 0, stream>>>(atom_out, ln_w, W1_1, W2, batch_idx, out, N);
}

// Round 5
// 70.933 us; speedup vs baseline: 1.0202x; 1.0202x over previous
//
#include <hip/hip_runtime.h>
#include <hip/hip_bf16.h>

#define WPB 2                 // waves per block
#define BLOCK (WPB * 64)
#define GRID 768              // 3 blocks/CU (LDS-limited) x 256 CU, fully resident

typedef __attribute__((ext_vector_type(8))) short s16x8;   // 8 bf16 (4 VGPRs)
typedef __attribute__((ext_vector_type(4))) float f32x4;   // 16B / MFMA acc

// async global->LDS, 16B per lane, LDS dest = uniform base + lane*16
#define GLL16(gp, lp) __builtin_amdgcn_global_load_lds( \
    (const __attribute__((address_space(1))) void*)(gp), \
    (__attribute__((address_space(3))) void*)(lp), 16, 0, 0)

__device__ __forceinline__ float wave_sum64(float v) {
#pragma unroll
    for (int m = 32; m >= 1; m >>= 1) v += __shfl_xor(v, m, 64);
    return v;
}

__device__ __forceinline__ short bf16b(float x) {          // f32 -> bf16 (RNE)
    union { float f; unsigned u; } c; c.f = x;
    unsigned r = c.u + 0x7FFFu + ((c.u >> 16) & 1u);
    return (short)(r >> 16);
}

__global__ __launch_bounds__(BLOCK, 2) void vecout_mfma(
    const float* __restrict__ atom_out,   // [N,480]; 1e block = cols 128..319
    const float* __restrict__ ln_w,       // [224]; 1e weights at 128..191
    const float* __restrict__ W1_1,       // [64,64] row-major [u][v]
    const float* __restrict__ W2,         // [64]
    const int*   __restrict__ batch_idx,  // [N], sorted
    float* __restrict__ out,              // [B,3]
    int N)
{
    // per-wave DOUBLE 12KB staging buffers (2-deep pipeline)
    __shared__ __align__(16) char Ash[WPB][2][12288];
    __shared__ float invsh[WPB][16];

    const int lane  = threadIdx.x & 63;
    const int wid   = threadIdx.x >> 6;
    const int col   = lane & 15;          // B col / C col (v within tile)
    const int kgrp  = lane >> 4;          // k-group
    const int atomi = lane & 15;          // A row (atom-local)

    // ---- balanced contiguous group partition across all waves ----
    const int NG  = (N + 15) >> 4;
    const int NW  = gridDim.x * WPB;
    const int w   = blockIdx.x * WPB + wid;
    const int cpw = NG / NW, rem = NG % NW;
    const int g0  = w * cpw + min(w, rem);
    const int cnt = cpw + (w < rem ? 1 : 0);
    if (cnt <= 0) return;                 // no block barriers -> safe
    const int gend = g0 + cnt;

    // ---- B fragments: W'[k][v] = W1_1[k][v] * ln_w[128+k] * (1/sqrt(64)) ----
    s16x8 Bf[2][4];
#pragma unroll
    for (int kt = 0; kt < 2; ++kt)
#pragma unroll
        for (int nt = 0; nt < 4; ++nt) {
            s16x8 b;
#pragma unroll
            for (int j = 0; j < 8; ++j) {
                int k = kt * 32 + kgrp * 8 + j;
                float wgt = W1_1[k * 64 + nt * 16 + col] * ln_w[128 + k] * 0.125f;
                b[j] = bf16b(wgt);
            }
            Bf[kt][nt] = b;
        }
    float w2r[4];
#pragma unroll
    for (int nt = 0; nt < 4; ++nt) w2r[nt] = W2[nt * 16 + col] * 0.125f;

    // ---- per-instr global source offsets within a group's 30720B span ----
    // LDS phys P = c*1024 + lane*16 ; row = P/768 (row = 6 cache lines, XOR of
    // bits 4..6 stays inside one line); logical L = P ^ ((row&7)<<4).
    int prec[12];
#pragma unroll
    for (int c = 0; c < 12; ++c) {
        int P   = c * 1024 + lane * 16;
        int row = P / 768;
        int L   = P ^ ((row & 7) << 4);
        prec[c] = row * 1920 + 512 + (L - row * 768);   // bytes from group base
    }

    const char* gb = (const char*)atom_out;
    const unsigned key   = (unsigned)(atomi & 7) << 4;
    const unsigned base0 = (unsigned)(atomi * 768 + kgrp * 96);

    float acc[4][3];
#pragma unroll
    for (int r = 0; r < 4; ++r) { acc[r][0] = 0.f; acc[r][1] = 0.f; acc[r][2] = 0.f; }
    int accb = batch_idx[g0 * 16];

    auto flushAcc = [&]() {
        float s0 = acc[0][0] + acc[1][0] + acc[2][0] + acc[3][0];
        float s1 = acc[0][1] + acc[1][1] + acc[2][1] + acc[3][1];
        float s2 = acc[0][2] + acc[1][2] + acc[2][2] + acc[3][2];
        s0 = wave_sum64(s0); s1 = wave_sum64(s1); s2 = wave_sum64(s2);
        if (lane == 0) {
            // e3nn (y,z,x) -> (x,y,z): out0=c2, out1=c0, out2=c1
            atomicAdd(&out[accb * 3 + 0], s2);
            atomicAdd(&out[accb * 3 + 1], s0);
            atomicAdd(&out[accb * 3 + 2], s1);
        }
#pragma unroll
        for (int r = 0; r < 4; ++r) { acc[r][0] = 0.f; acc[r][1] = 0.f; acc[r][2] = 0.f; }
    };

    auto issueG = [&](int g, int buf) {
        char* Ab = &Ash[wid][buf][0];
        if (((g + 1) << 4) <= N) {        // full group
            const char* p = gb + (size_t)g * 30720;
#pragma unroll
            for (int c = 0; c < 12; ++c)
                GLL16(p + prec[c], Ab + c * 1024);
        } else {                           // tail: clamp rows to N-1
#pragma unroll
            for (int c = 0; c < 12; ++c) {
                int P   = c * 1024 + lane * 16;
                int row = P / 768;
                int off = (P ^ ((row & 7) << 4)) - row * 768;
                int ga  = min(g * 16 + row, N - 1);
                GLL16(gb + (size_t)ga * 1920 + 512 + off, Ab + c * 1024);
            }
        }
    };

    // ---- prologue: 2-deep prefetch ----
    issueG(g0, 0);
    if (g0 + 1 < gend) issueG(g0 + 1, 1);

    for (int g = g0; g < gend; ++g) {
        const int cur = (g - g0) & 1;
        const int a   = g * 16;
        const bool has_next = (g + 1 < gend);

        // counted wait: previous buffer landed, next group's 12 stay in flight
        if (has_next) asm volatile("s_waitcnt vmcnt(12)" ::: "memory");
        else          asm volatile("s_waitcnt vmcnt(0)"  ::: "memory");

        char* Ab = &Ash[wid][cur][0];

        // ---- LDS -> regs: lane's 48 floats = two contiguous 96B runs ----
        float F[48];
#pragma unroll
        for (int kt = 0; kt < 2; ++kt)
#pragma unroll
            for (int s = 0; s < 6; ++s) {
                unsigned ad = (base0 + (unsigned)(kt * 384 + s * 16)) ^ key;
                f32x4 t = *(const f32x4*)(Ab + ad);
                int i = (kt * 6 + s) * 4;
                F[i + 0] = t[0]; F[i + 1] = t[1]; F[i + 2] = t[2]; F[i + 3] = t[3];
            }
        asm volatile("s_waitcnt lgkmcnt(0)" ::: "memory"); // buffer now dead

        if (g + 2 < gend) issueG(g + 2, cur);   // refill freed buffer

        // ---- per-atom RMS norm (4 lanes/atom share via 2 shfls) ----
        float nrm = 0.f;
#pragma unroll
        for (int i = 0; i < 48; ++i) nrm += F[i] * F[i];
        nrm += __shfl_xor(nrm, 16, 64);
        nrm += __shfl_xor(nrm, 32, 64);
        float inv = rsqrtf(nrm * (1.0f / 64.0f) + 1e-5f);
        if (lane < 16) invsh[wid][lane] = inv;

        // ---- build A fragments in-register ----
        s16x8 Af[3][2];
#pragma unroll
        for (int c = 0; c < 3; ++c)
#pragma unroll
            for (int kt = 0; kt < 2; ++kt) {
                s16x8 fr;
#pragma unroll
                for (int j = 0; j < 8; ++j) fr[j] = bf16b(F[kt * 24 + 3 * j + c]);
                Af[c][kt] = fr;
            }

        // ---- MFMA: D[atom][v] = sum_u f[atom][u][c] * W'[u][v] ----
        f32x4 Cf[3][4];
#pragma unroll
        for (int c = 0; c < 3; ++c)
#pragma unroll
            for (int nt = 0; nt < 4; ++nt) {
                f32x4 z = {0.f, 0.f, 0.f, 0.f};
                z = __builtin_amdgcn_mfma_f32_16x16x32_bf16(Af[c][0], Bf[0][nt], z, 0, 0, 0);
                z = __builtin_amdgcn_mfma_f32_16x16x32_bf16(Af[c][1], Bf[1][nt], z, 0, 0, 0);
                Cf[c][nt] = z;
            }

        // ---- epilogue: gate + W2; 3 comps of (atom,v) in same lane/reg ----
        float invA[4];
#pragma unroll
        for (int r = 0; r < 4; ++r) invA[r] = invsh[wid][kgrp * 4 + r];

        float part[4][3];
#pragma unroll
        for (int r = 0; r < 4; ++r) {
            part[r][0] = 0.f; part[r][1] = 0.f; part[r][2] = 0.f;
            float iv = invA[r];
#pragma unroll
            for (int nt = 0; nt < 4; ++nt) {
                float g0v = Cf[0][nt][r] * iv;
                float g1v = Cf[1][nt][r] * iv;
                float g2v = Cf[2][nt][r] * iv;
                float q  = g0v * g0v + g1v * g1v + g2v * g2v;
                float nr = sqrtf(q + 1e-12f);
                float sg = 1.f / (1.f + __expf(-nr));
                float t  = sg * w2r[nt];
                part[r][0] += g0v * t; part[r][1] += g1v * t; part[r][2] += g2v * t;
            }
            if (a + kgrp * 4 + r >= N) { part[r][0] = 0.f; part[r][1] = 0.f; part[r][2] = 0.f; }
        }

        // ---- segment accumulation (batch_idx sorted) ----
        int bfst = batch_idx[a];
        int blst = batch_idx[min(a + 15, N - 1)];
        if (bfst == blst) {
            if (bfst != accb) { flushAcc(); accb = bfst; }
#pragma unroll
            for (int r = 0; r < 4; ++r) {
                acc[r][0] += part[r][0]; acc[r][1] += part[r][1]; acc[r][2] += part[r][2];
            }
        } else {
            flushAcc();
#pragma unroll
            for (int r = 0; r < 4; ++r) {
                float c0 = part[r][0], c1 = part[r][1], c2 = part[r][2];
#pragma unroll
                for (int m = 1; m < 16; m <<= 1) {
                    c0 += __shfl_xor(c0, m, 64);
                    c1 += __shfl_xor(c1, m, 64);
                    c2 += __shfl_xor(c2, m, 64);
                }
                int ai = a + kgrp * 4 + r;
                if (col == 0 && ai < N) {
                    int b = batch_idx[ai];
                    atomicAdd(&out[b * 3 + 0], c2);
                    atomicAdd(&out[b * 3 + 1], c0);
                    atomicAdd(&out[b * 3 + 2], c1);
                }
            }
            accb = blst;
        }
    }

    flushAcc();
}

extern "C" void kernel_launch(void* const* d_in, const int* in_sizes, int n_in,
                              void* d_out, int out_size, void* d_ws, size_t ws_size,
                              hipStream_t stream) {
    const float* atom_out  = (const float*)d_in[0];
    const float* ln_w      = (const float*)d_in[2];
    const float* W1_1      = (const float*)d_in[5];
    const float* W2        = (const float*)d_in[7];
    const int*   batch_idx = (const int*)d_in[9];
    float* out = (float*)d_out;

    const int N = in_sizes[0] / 480;

    hipMemsetAsync(d_out, 0, (size_t)out_size * sizeof(float), stream);

    vecout_mfma<<<GRID, BLOCK, 0, stream>>>(atom_out, ln_w, W1_1, W2, batch_idx, out, N);
}

// Round 6
// 70.037 us; speedup vs baseline: 1.0333x; 1.0128x over previous
//
#include <hip/hip_runtime.h>
#include <hip/hip_bf16.h>

#define WPB 2                 // waves per block
#define BLOCK (WPB * 64)
#define GRID 768              // 3 blocks/CU (48KB LDS each) x 256 CU, resident

typedef __attribute__((ext_vector_type(8))) short s16x8;   // 8 bf16 (4 VGPRs)
typedef __attribute__((ext_vector_type(4))) float f32x4;   // 16B / MFMA acc

// async global->LDS, 16B per lane, LDS dest = uniform base + lane*16
#define GLL16(gp, lp) __builtin_amdgcn_global_load_lds( \
    (const __attribute__((address_space(1))) void*)(gp), \
    (__attribute__((address_space(3))) void*)(lp), 16, 0, 0)

__device__ __forceinline__ float wave_sum64(float v) {
#pragma unroll
    for (int m = 32; m >= 1; m >>= 1) v += __shfl_xor(v, m, 64);
    return v;
}

__device__ __forceinline__ short bf16b(float x) {          // f32 -> bf16 (RNE)
    union { float f; unsigned u; } c; c.f = x;
    unsigned r = c.u + 0x7FFFu + ((c.u >> 16) & 1u);
    return (short)(r >> 16);
}

// opaque LDS read: invisible to SIInsertWaitcnts -> no auto vmcnt(0) drain.
// Caller MUST bracket with s_waitcnt lgkmcnt(0) + sched_barrier before use.
__device__ __forceinline__ f32x4 lds_read_b128(unsigned addr) {
    f32x4 r;
    asm volatile("ds_read_b128 %0, %1" : "=v"(r) : "v"(addr));
    return r;
}

__global__ __launch_bounds__(BLOCK, 2) void vecout_mfma(
    const float* __restrict__ atom_out,   // [N,480]; 1e block = cols 128..319
    const float* __restrict__ ln_w,       // [224]; 1e weights at 128..191
    const float* __restrict__ W1_1,       // [64,64] row-major [u][v]
    const float* __restrict__ W2,         // [64]
    const int*   __restrict__ batch_idx,  // [N], sorted
    float* __restrict__ out,              // [B,3]
    int N)
{
    // per-wave DOUBLE 12KB staging buffers; accessed ONLY via gll + asm reads
    __shared__ __align__(16) char Ash[WPB][2][12288];

    const int lane  = threadIdx.x & 63;
    const int wid   = threadIdx.x >> 6;
    const int col   = lane & 15;          // B col / C col (v within tile)
    const int kgrp  = lane >> 4;          // k-group
    const int atomi = lane & 15;          // A row (atom-local)
    const unsigned key   = (unsigned)(atomi & 7) << 4;
    const unsigned base0 = (unsigned)(atomi * 768 + kgrp * 96);

    // LDS byte offset of this wave's buffer pair
    const unsigned ab0 = (unsigned)(size_t)
        (__attribute__((address_space(3))) char*)&Ash[wid][0][0];

    // ---- balanced contiguous group partition across all waves ----
    const int NG  = (N + 15) >> 4;
    const int NW  = gridDim.x * WPB;
    const int w   = blockIdx.x * WPB + wid;
    const int cpw = NG / NW, rem = NG % NW;
    const int g0  = w * cpw + min(w, rem);
    const int cnt = cpw + (w < rem ? 1 : 0);
    if (cnt <= 0) return;                 // no block barriers -> safe
    const int gend = g0 + cnt;

    // ---- B fragments: W'[k][v] = W1_1[k][v] * ln_w[128+k] * (1/sqrt(64)) ----
    s16x8 Bf[2][4];
#pragma unroll
    for (int kt = 0; kt < 2; ++kt)
#pragma unroll
        for (int nt = 0; nt < 4; ++nt) {
            s16x8 b;
#pragma unroll
            for (int j = 0; j < 8; ++j) {
                int k = kt * 32 + kgrp * 8 + j;
                float wgt = W1_1[k * 64 + nt * 16 + col] * ln_w[128 + k] * 0.125f;
                b[j] = bf16b(wgt);
            }
            Bf[kt][nt] = b;
        }
    float w2r[4];
#pragma unroll
    for (int nt = 0; nt < 4; ++nt) w2r[nt] = W2[nt * 16 + col] * 0.125f;

    // ---- per-instr global source offsets within a group's 30720B span ----
    int prec[12];
#pragma unroll
    for (int c = 0; c < 12; ++c) {
        int P   = c * 1024 + lane * 16;
        int row = P / 768;
        int L   = P ^ ((row & 7) << 4);
        prec[c] = row * 1920 + 512 + (L - row * 768);
    }

    const char* gb = (const char*)atom_out;

    float acc[4][3];
#pragma unroll
    for (int r = 0; r < 4; ++r) { acc[r][0] = 0.f; acc[r][1] = 0.f; acc[r][2] = 0.f; }
    int accb = batch_idx[__builtin_amdgcn_readfirstlane(g0 * 16)];

    auto flushAcc = [&]() {
        float s0 = acc[0][0] + acc[1][0] + acc[2][0] + acc[3][0];
        float s1 = acc[0][1] + acc[1][1] + acc[2][1] + acc[3][1];
        float s2 = acc[0][2] + acc[1][2] + acc[2][2] + acc[3][2];
        s0 = wave_sum64(s0); s1 = wave_sum64(s1); s2 = wave_sum64(s2);
        if (lane == 0) {
            // e3nn (y,z,x) -> (x,y,z): out0=c2, out1=c0, out2=c1
            atomicAdd(&out[accb * 3 + 0], s2);
            atomicAdd(&out[accb * 3 + 1], s0);
            atomicAdd(&out[accb * 3 + 2], s1);
        }
#pragma unroll
        for (int r = 0; r < 4; ++r) { acc[r][0] = 0.f; acc[r][1] = 0.f; acc[r][2] = 0.f; }
    };

    auto issueG = [&](int g, int buf) {
        char* Ab = &Ash[wid][buf][0];
        if (((g + 1) << 4) <= N) {        // full group
            const char* p = gb + (size_t)g * 30720;
#pragma unroll
            for (int c = 0; c < 12; ++c)
                GLL16(p + prec[c], Ab + c * 1024);
        } else {                           // tail: clamp rows to N-1
#pragma unroll
            for (int c = 0; c < 12; ++c) {
                int P   = c * 1024 + lane * 16;
                int row = P / 768;
                int off = (P ^ ((row & 7) << 4)) - row * 768;
                int ga  = min(g * 16 + row, N - 1);
                GLL16(gb + (size_t)ga * 1920 + 512 + off, Ab + c * 1024);
            }
        }
    };

    // ---- prologue: 2-deep prefetch ----
    issueG(g0, 0);
    if (g0 + 1 < gend) issueG(g0 + 1, 1);

    for (int g = g0; g < gend; ++g) {
        const int cur = (g - g0) & 1;
        const int a   = g * 16;

        // counted wait: g's 12 loads landed; g+1's 12 stay in flight.
        // (flush atomics are always issued BEFORE the following group's glls,
        //  so vmcnt(12) retires [g's 12 + old atomics] exactly.)
        if (g + 1 < gend) asm volatile("s_waitcnt vmcnt(12)" ::: "memory");
        else              asm volatile("s_waitcnt vmcnt(0)"  ::: "memory");
        __builtin_amdgcn_sched_barrier(0);

        const unsigned abase = ab0 + (unsigned)cur * 12288u;

        // ---- LDS -> regs via opaque asm reads; norm + bf16 A-frags on the fly ----
        float nrm = 0.f;
        s16x8 Af[3][2];
#pragma unroll
        for (int kt = 0; kt < 2; ++kt) {
            f32x4 V[6];
#pragma unroll
            for (int s = 0; s < 6; ++s) {
                unsigned ad = abase + ((base0 + (unsigned)(kt * 384 + s * 16)) ^ key);
                V[s] = lds_read_b128(ad);
            }
            asm volatile("s_waitcnt lgkmcnt(0)" ::: "memory");
            __builtin_amdgcn_sched_barrier(0);
#pragma unroll
            for (int s = 0; s < 6; ++s)
#pragma unroll
                for (int q = 0; q < 4; ++q) {
                    int d = s * 4 + q;                 // local elem = 3*j + c
                    float v = V[s][q];
                    nrm += v * v;
                    Af[d % 3][kt][d / 3] = bf16b(v);
                }
        }

        // ---- per-atom RMS norm (4 lanes/atom share via 2 shfls) ----
        nrm += __shfl_xor(nrm, 16, 64);
        nrm += __shfl_xor(nrm, 32, 64);
        float inv = rsqrtf(nrm * (1.0f / 64.0f) + 1e-5f);
        float invA[4];
#pragma unroll
        for (int r = 0; r < 4; ++r) invA[r] = __shfl(inv, kgrp * 4 + r, 64);

        // ---- MFMA + epilogue per v-tile (keeps Cf footprint at 12 regs) ----
        float part[4][3];
#pragma unroll
        for (int r = 0; r < 4; ++r) { part[r][0] = 0.f; part[r][1] = 0.f; part[r][2] = 0.f; }
#pragma unroll
        for (int nt = 0; nt < 4; ++nt) {
            f32x4 C0 = {0.f,0.f,0.f,0.f}, C1 = {0.f,0.f,0.f,0.f}, C2 = {0.f,0.f,0.f,0.f};
            C0 = __builtin_amdgcn_mfma_f32_16x16x32_bf16(Af[0][0], Bf[0][nt], C0, 0, 0, 0);
            C0 = __builtin_amdgcn_mfma_f32_16x16x32_bf16(Af[0][1], Bf[1][nt], C0, 0, 0, 0);
            C1 = __builtin_amdgcn_mfma_f32_16x16x32_bf16(Af[1][0], Bf[0][nt], C1, 0, 0, 0);
            C1 = __builtin_amdgcn_mfma_f32_16x16x32_bf16(Af[1][1], Bf[1][nt], C1, 0, 0, 0);
            C2 = __builtin_amdgcn_mfma_f32_16x16x32_bf16(Af[2][0], Bf[0][nt], C2, 0, 0, 0);
            C2 = __builtin_amdgcn_mfma_f32_16x16x32_bf16(Af[2][1], Bf[1][nt], C2, 0, 0, 0);
#pragma unroll
            for (int r = 0; r < 4; ++r) {
                float iv  = invA[r];
                float g0v = C0[r] * iv;
                float g1v = C1[r] * iv;
                float g2v = C2[r] * iv;
                float q  = g0v * g0v + g1v * g1v + g2v * g2v;
                float nr = sqrtf(q + 1e-12f);
                float sg = 1.f / (1.f + __expf(-nr));
                float t  = sg * w2r[nt];
                part[r][0] += g0v * t; part[r][1] += g1v * t; part[r][2] += g2v * t;
            }
        }
#pragma unroll
        for (int r = 0; r < 4; ++r)
            if (a + kgrp * 4 + r >= N) { part[r][0] = 0.f; part[r][1] = 0.f; part[r][2] = 0.f; }

        // ---- segment accumulation: batch ids via SCALAR loads (lgkm path,
        //      keeps the vmcnt prefetch queue untouched) ----
        int bfst = batch_idx[__builtin_amdgcn_readfirstlane(a)];
        int blst = batch_idx[__builtin_amdgcn_readfirstlane(min(a + 15, N - 1))];
        if (bfst == blst) {
            if (bfst != accb) { flushAcc(); accb = bfst; }
#pragma unroll
            for (int r = 0; r < 4; ++r) {
                acc[r][0] += part[r][0]; acc[r][1] += part[r][1]; acc[r][2] += part[r][2];
            }
        } else {
            flushAcc();
#pragma unroll
            for (int r = 0; r < 4; ++r) {
                float c0 = part[r][0], c1 = part[r][1], c2 = part[r][2];
#pragma unroll
                for (int m = 1; m < 16; m <<= 1) {
                    c0 += __shfl_xor(c0, m, 64);
                    c1 += __shfl_xor(c1, m, 64);
                    c2 += __shfl_xor(c2, m, 64);
                }
                int ai = a + kgrp * 4 + r;
                if (col == 0 && ai < N) {
                    int b = batch_idx[ai];
                    atomicAdd(&out[b * 3 + 0], c2);
                    atomicAdd(&out[b * 3 + 1], c0);
                    atomicAdd(&out[b * 3 + 2], c1);
                }
            }
            accb = blst;
        }

        // ---- refill freed buffer LAST (after all this group's atomics) so
        //      the next iteration's vmcnt(12) counts stay exact ----
        if (g + 2 < gend) issueG(g + 2, cur);
    }

    flushAcc();
}

extern "C" void kernel_launch(void* const* d_in, const int* in_sizes, int n_in,
                              void* d_out, int out_size, void* d_ws, size_t ws_size,
                              hipStream_t stream) {
    const float* atom_out  = (const float*)d_in[0];
    const float* ln_w      = (const float*)d_in[2];
    const float* W1_1      = (const float*)d_in[5];
    const float* W2        = (const float*)d_in[7];
    const int*   batch_idx = (const int*)d_in[9];
    float* out = (float*)d_out;

    const int N = in_sizes[0] / 480;

    hipMemsetAsync(d_out, 0, (size_t)out_size * sizeof(float), stream);

    vecout_mfma<<<GRID, BLOCK, 0, stream>>>(atom_out, ln_w, W1_1, W2, batch_idx, out, N);
}